// Round 11
// baseline (294.799 us; speedup 1.0000x reference)
//
#include <hip/hip_runtime.h>
#include <cstddef>
#include <cstdint>

// ---------------- bf16 helpers ----------------

__device__ __forceinline__ unsigned short f2bf(float f) {
    uint32_t u = __float_as_uint(f);
    u += 0x7FFFu + ((u >> 16) & 1u);
    return (unsigned short)(u >> 16);
}
__device__ __forceinline__ uint32_t f2bf2(float lo, float hi) {
    return (uint32_t)f2bf(lo) | ((uint32_t)f2bf(hi) << 16);
}
__device__ __forceinline__ float bf2f(unsigned short b) {
    return __uint_as_float(((uint32_t)b) << 16);
}
__device__ __forceinline__ float bf2f_lo(uint32_t v) {
    return __uint_as_float(v << 16);
}
__device__ __forceinline__ float bf2f_hi(uint32_t v) {
    return __uint_as_float(v & 0xFFFF0000u);
}

typedef __attribute__((ext_vector_type(8))) short bf16x8;
typedef __attribute__((ext_vector_type(4))) float f32x4;

// ---------------- CSR construction ----------------

__global__ void count_edges_k(const int* __restrict__ ei, int* __restrict__ counts,
                              int E, int N) {
    int e = blockIdx.x * blockDim.x + threadIdx.x;
    int tot = E + N;
    if (e >= tot) return;
    int d = (e < E) ? ei[E + e] : (e - E);
    atomicAdd(&counts[d], 1);
}

// multi-block scan, phase 1: per-1024-chunk sums
__global__ __launch_bounds__(1024) void scan_bsum_k(const int* __restrict__ counts,
                                                    int* __restrict__ bsum, int N) {
    __shared__ int wsum[16];
    int tid = threadIdx.x, lane = tid & 63, w = tid >> 6;
    int i = blockIdx.x * 1024 + tid;
    int x = (i < N) ? counts[i] : 0;
    #pragma unroll
    for (int d = 32; d; d >>= 1) x += __shfl_xor(x, d, 64);
    if (lane == 0) wsum[w] = x;
    __syncthreads();
    if (tid == 0) {
        int s = 0;
        #pragma unroll
        for (int k = 0; k < 16; ++k) s += wsum[k];
        bsum[blockIdx.x] = s;
    }
}

// phase 2: exclusive scan of block sums (nb <= 64)
__global__ void scan_boff_k(const int* __restrict__ bsum, int* __restrict__ boff, int nb) {
    int lane = threadIdx.x;
    int v = (lane < nb) ? bsum[lane] : 0;
    int x = v;
    #pragma unroll
    for (int d = 1; d < 64; d <<= 1) {
        int t = __shfl_up(x, d, 64);
        if (lane >= d) x += t;
    }
    if (lane < nb) boff[lane] = x - v;
}

// phase 3: per-chunk scan + global base -> offs/cursor
__global__ __launch_bounds__(1024) void scan_final_k(const int* __restrict__ counts,
                                                     const int* __restrict__ boff,
                                                     int* __restrict__ offs,
                                                     int* __restrict__ cursor, int N) {
    __shared__ int wsum[16];
    int tid = threadIdx.x, lane = tid & 63, w = tid >> 6;
    int i = blockIdx.x * 1024 + tid;
    int v = (i < N) ? counts[i] : 0;
    int x = v;
    #pragma unroll
    for (int d = 1; d < 64; d <<= 1) {
        int t = __shfl_up(x, d, 64);
        if (lane >= d) x += t;
    }
    if (lane == 63) wsum[w] = x;
    __syncthreads();
    if (tid == 0) {
        int run = 0;
        #pragma unroll
        for (int k = 0; k < 16; ++k) { run += wsum[k]; wsum[k] = run; }
    }
    __syncthreads();
    int excl = (x - v) + (w > 0 ? wsum[w - 1] : 0) + boff[blockIdx.x];
    if (i < N) { cursor[i] = excl; offs[i + 1] = excl + v; }
    if (i == 0) offs[0] = 0;
}

__global__ void fill_csr_k(const int* __restrict__ ei, int* __restrict__ cursor,
                           int* __restrict__ csr_src, int E, int N) {
    int e = blockIdx.x * blockDim.x + threadIdx.x;
    int tot = E + N;
    if (e >= tot) return;
    int s, d;
    if (e < E) { s = ei[e]; d = ei[E + e]; }
    else       { s = e - E; d = s; }
    int pos = atomicAdd(&cursor[d], 1);
    csr_src[pos] = s;
}

// ---------------- converts ----------------

// W [K][Nc] f32 -> WT [Nc][K] bf16
__global__ void wt_k(const float* __restrict__ W, unsigned short* __restrict__ WT,
                     int K, int Nc) {
    int n = blockIdx.x;
    for (int k = threadIdx.x; k < K; k += blockDim.x)
        WT[(size_t)n * K + k] = f2bf(W[(size_t)k * Nc + n]);
}

// ---------------- generalized MFMA bf16 GEMM ----------------
// C[M,Nc] = A[M,KD] @ BT[Nc,KD]^T, 128xBN tile, 4 waves (2x2), BK=32.
// AF32: A is f32, converted during staging. OUTB: bf16 out; else f32 (+bias).
// FUSEATT (BN=128, Nc=256, H=4): fused al_s/al_d from f32 acc in epilogue.

template<int KD, int BN, int NI, bool AF32, bool OUTB, bool HASBIAS, bool FUSEATT>
__global__ __launch_bounds__(256) void gemm_mfma_k(
    const unsigned short* __restrict__ Ab,
    const float* __restrict__ Af,
    const unsigned short* __restrict__ BT,
    const float* __restrict__ bias,
    const float* __restrict__ att_s,
    const float* __restrict__ att_d,
    float* __restrict__ al_s,
    float* __restrict__ al_d,
    unsigned short* __restrict__ Cb,
    float* __restrict__ Cf,
    int M, int Nc)
{
    const int SA = 40;
    __shared__ unsigned short As[128 * SA];
    __shared__ unsigned short Bs[BN * SA];
    int tid = threadIdx.x;
    int lane = tid & 63, wid = tid >> 6;
    int wm = wid >> 1, wn = wid & 1;
    int bm = blockIdx.x * 128, bn = blockIdx.y * BN;

    f32x4 acc[4][NI];
    #pragma unroll
    for (int mi = 0; mi < 4; ++mi)
        #pragma unroll
        for (int ni = 0; ni < NI; ++ni) {
            acc[mi][ni][0] = 0.f; acc[mi][ni][1] = 0.f;
            acc[mi][ni][2] = 0.f; acc[mi][ni][3] = 0.f;
        }

    int srow = tid >> 2;   // 0..63
    int skc  = tid & 3;    // 8-elem chunk within BK=32

    for (int k0 = 0; k0 < KD; k0 += 32) {
        #pragma unroll
        for (int q = 0; q < 2; ++q) {
            int row = q * 64 + srow;
            int gr = bm + row;
            int4 av = make_int4(0, 0, 0, 0);
            if (AF32) {
                float4 a0 = make_float4(0.f, 0.f, 0.f, 0.f), a1 = a0;
                if (gr < M) {
                    a0 = *(const float4*)&Af[(size_t)gr * KD + k0 + skc * 8];
                    a1 = *(const float4*)&Af[(size_t)gr * KD + k0 + skc * 8 + 4];
                }
                av.x = (int)f2bf2(a0.x, a0.y);
                av.y = (int)f2bf2(a0.z, a0.w);
                av.z = (int)f2bf2(a1.x, a1.y);
                av.w = (int)f2bf2(a1.z, a1.w);
            } else {
                if (gr < M) av = *(const int4*)&Ab[(size_t)gr * KD + k0 + skc * 8];
            }
            *(int4*)&As[row * SA + skc * 8] = av;
        }
        #pragma unroll
        for (int q = 0; q < BN / 64; ++q) {
            int row = q * 64 + srow;
            int4 bv = *(const int4*)&BT[(size_t)(bn + row) * KD + k0 + skc * 8];
            *(int4*)&Bs[row * SA + skc * 8] = bv;
        }
        __syncthreads();

        bf16x8 af[4], bfv[NI];
        #pragma unroll
        for (int mi = 0; mi < 4; ++mi)
            af[mi] = *(const bf16x8*)&As[(wm * 64 + mi * 16 + (lane & 15)) * SA + (lane >> 4) * 8];
        #pragma unroll
        for (int ni = 0; ni < NI; ++ni)
            bfv[ni] = *(const bf16x8*)&Bs[(wn * (NI * 16) + ni * 16 + (lane & 15)) * SA + (lane >> 4) * 8];
        #pragma unroll
        for (int mi = 0; mi < 4; ++mi)
            #pragma unroll
            for (int ni = 0; ni < NI; ++ni)
                acc[mi][ni] = __builtin_amdgcn_mfma_f32_16x16x32_bf16(af[mi], bfv[ni], acc[mi][ni], 0, 0, 0);
        __syncthreads();
    }

    // D: col = lane&15 (+16*ni), row = (lane>>4)*4 + reg
    #pragma unroll
    for (int mi = 0; mi < 4; ++mi) {
        #pragma unroll
        for (int j = 0; j < 4; ++j) {
            int row = bm + wm * 64 + mi * 16 + (lane >> 4) * 4 + j;
            if (row >= M) continue;
            #pragma unroll
            for (int ni = 0; ni < NI; ++ni) {
                int col = bn + wn * (NI * 16) + ni * 16 + (lane & 15);
                if (OUTB) {
                    Cb[(size_t)row * Nc + col] = f2bf(acc[mi][ni][j]);
                } else {
                    float v = acc[mi][ni][j] + (HASBIAS ? bias[col] : 0.f);
                    Cf[(size_t)row * Nc + col] = v;
                }
            }
        }
    }

    if (FUSEATT) {
        int head = (bn >> 6) + wn;
        float asv[NI], adv[NI];
        #pragma unroll
        for (int ni = 0; ni < NI; ++ni) {
            int c = head * 64 + ni * 16 + (lane & 15);
            asv[ni] = att_s[c];
            adv[ni] = att_d[c];
        }
        #pragma unroll
        for (int mi = 0; mi < 4; ++mi) {
            #pragma unroll
            for (int j = 0; j < 4; ++j) {
                float sp = 0.f, dp = 0.f;
                #pragma unroll
                for (int ni = 0; ni < NI; ++ni) {
                    sp += acc[mi][ni][j] * asv[ni];
                    dp += acc[mi][ni][j] * adv[ni];
                }
                #pragma unroll
                for (int d = 1; d < 16; d <<= 1) {
                    sp += __shfl_xor(sp, d, 64);
                    dp += __shfl_xor(dp, d, 64);
                }
                int row = bm + wm * 64 + mi * 16 + (lane >> 4) * 4 + j;
                if ((lane & 15) == 0 && row < M) {
                    al_s[(size_t)row * 4 + head] = sp;
                    al_d[(size_t)row * 4 + head] = dp;
                }
            }
        }
    }
}

// ---------------- 64x64 MFMA GEMM (GEMM2) ----------------

__global__ __launch_bounds__(256) void gemm_mfma64_k(
    const unsigned short* __restrict__ Ab,
    const unsigned short* __restrict__ BT,
    unsigned short* __restrict__ Cb,
    int M)
{
    const int SA = 40;
    __shared__ unsigned short As[64 * SA];
    __shared__ unsigned short Bs[64 * SA];
    int tid = threadIdx.x;
    int lane = tid & 63, wid = tid >> 6;
    int wm = wid >> 1, wn = wid & 1;
    int bm = blockIdx.x * 64;

    f32x4 acc[2][2];
    #pragma unroll
    for (int mi = 0; mi < 2; ++mi)
        #pragma unroll
        for (int ni = 0; ni < 2; ++ni) {
            acc[mi][ni][0] = 0.f; acc[mi][ni][1] = 0.f;
            acc[mi][ni][2] = 0.f; acc[mi][ni][3] = 0.f;
        }

    int srow = tid >> 2;
    int skc  = tid & 3;

    for (int k0 = 0; k0 < 256; k0 += 32) {
        {
            int gr = bm + srow;
            int4 av = make_int4(0, 0, 0, 0);
            if (gr < M) av = *(const int4*)&Ab[(size_t)gr * 256 + k0 + skc * 8];
            *(int4*)&As[srow * SA + skc * 8] = av;
            int4 bv = *(const int4*)&BT[(size_t)srow * 256 + k0 + skc * 8];
            *(int4*)&Bs[srow * SA + skc * 8] = bv;
        }
        __syncthreads();

        bf16x8 af[2], bfv[2];
        #pragma unroll
        for (int mi = 0; mi < 2; ++mi)
            af[mi] = *(const bf16x8*)&As[(wm * 32 + mi * 16 + (lane & 15)) * SA + (lane >> 4) * 8];
        #pragma unroll
        for (int ni = 0; ni < 2; ++ni)
            bfv[ni] = *(const bf16x8*)&Bs[(wn * 32 + ni * 16 + (lane & 15)) * SA + (lane >> 4) * 8];
        #pragma unroll
        for (int mi = 0; mi < 2; ++mi)
            #pragma unroll
            for (int ni = 0; ni < 2; ++ni)
                acc[mi][ni] = __builtin_amdgcn_mfma_f32_16x16x32_bf16(af[mi], bfv[ni], acc[mi][ni], 0, 0, 0);
        __syncthreads();
    }

    #pragma unroll
    for (int mi = 0; mi < 2; ++mi) {
        #pragma unroll
        for (int j = 0; j < 4; ++j) {
            int row = bm + wm * 32 + mi * 16 + (lane >> 4) * 4 + j;
            if (row >= M) continue;
            #pragma unroll
            for (int ni = 0; ni < 2; ++ni) {
                int col = wn * 32 + ni * 16 + (lane & 15);
                Cb[(size_t)row * 64 + col] = f2bf(acc[mi][ni][j]);
            }
        }
    }
}

// ---------------- per-node attention logits (bf16 input) ----------------

__global__ void att_b_k(const unsigned short* __restrict__ hb, const float* __restrict__ as_,
                        const float* __restrict__ ad_, float* __restrict__ al_s,
                        float* __restrict__ al_d, int H, int C) {
    int n = blockIdx.x;
    int t = threadIdx.x;
    int hd = t / C;
    int c = t % C;
    float hv = bf2f(hb[(size_t)n * H * C + t]);
    float ps = hv * as_[t];
    float pd = hv * ad_[t];
    #pragma unroll
    for (int d = 32; d > 0; d >>= 1) {
        ps += __shfl_down(ps, d, 64);
        pd += __shfl_down(pd, d, 64);
    }
    if (c == 0) {
        al_s[(size_t)n * H + hd] = ps;
        al_d[(size_t)n * H + hd] = pd;
    }
}

// ---------------- float4 helpers ----------------

__device__ __forceinline__ float4 shflx4(float4 v, int d) {
    float4 r;
    r.x = __shfl_xor(v.x, d, 64);
    r.y = __shfl_xor(v.y, d, 64);
    r.z = __shfl_xor(v.z, d, 64);
    r.w = __shfl_xor(v.w, d, 64);
    return r;
}
__device__ __forceinline__ float4 max4(float4 a, float4 b) {
    return make_float4(fmaxf(a.x, b.x), fmaxf(a.y, b.y), fmaxf(a.z, b.z), fmaxf(a.w, b.w));
}
__device__ __forceinline__ float sel4(float4 v, int i) {
    float ab = (i & 1) ? v.y : v.x;
    float cd = (i & 1) ? v.w : v.z;
    return (i & 2) ? cd : ab;
}
__device__ __forceinline__ float lrelu(float t) { return (t > 0.f) ? t : 0.2f * t; }

// ---------------- GAT agg, layer 1 (H=4, 256 ch, bf16 in/out) ----------------
// One wave per node. Gather: 2 edges/iter, 16B loads.
// lane = e2*32 + c8: e2 picks the edge subslot, c8 picks 8 channels (16B).
// Final shfl_xor(32) combines the two edge-partials; lanes e2==0 write.

__global__ __launch_bounds__(256) void gat_agg_h4b_k(
    const unsigned short* __restrict__ hb, const float* __restrict__ al_s,
    const float* __restrict__ al_d, const int* __restrict__ offs,
    const int* __restrict__ csr_src, const float* __restrict__ bias,
    unsigned short* __restrict__ outb, int N)
{
    __shared__ float4 alds[4][64];
    __shared__ int    slds[4][64];
    int w = threadIdx.x >> 6, lane = threadIdx.x & 63;
    int node = blockIdx.x * 4 + w;
    if (node >= N) return;
    int e2 = lane >> 5, c8 = lane & 31;
    int hd = c8 >> 3;                       // head of channels c8*8..c8*8+7
    int beg = offs[node], end = offs[node + 1];
    float4 ald4 = *(const float4*)&al_d[(size_t)node * 4];
    float4 m4 = make_float4(-1e30f, -1e30f, -1e30f, -1e30f);
    float4 z4 = make_float4(0.f, 0.f, 0.f, 0.f);
    float acc[8] = {};

    for (int base = beg; base < end; base += 64) {
        int cnt = min(64, end - base);
        int s = 0;
        float4 l4 = make_float4(-1e30f, -1e30f, -1e30f, -1e30f);
        if (lane < cnt) {
            s = csr_src[base + lane];
            float4 as4 = *(const float4*)&al_s[(size_t)s * 4];
            l4.x = lrelu(as4.x + ald4.x);
            l4.y = lrelu(as4.y + ald4.y);
            l4.z = lrelu(as4.z + ald4.z);
            l4.w = lrelu(as4.w + ald4.w);
        }
        float4 mc = l4;
        #pragma unroll
        for (int d = 32; d; d >>= 1) mc = max4(mc, shflx4(mc, d));
        float4 mn = max4(m4, mc);
        float4 p4;
        p4.x = __expf(l4.x - mn.x);   // 0 for inactive lanes
        p4.y = __expf(l4.y - mn.y);
        p4.z = __expf(l4.z - mn.z);
        p4.w = __expf(l4.w - mn.w);
        float4 zc = p4;
        #pragma unroll
        for (int d = 32; d; d >>= 1) {
            float4 t = shflx4(zc, d);
            zc.x += t.x; zc.y += t.y; zc.z += t.z; zc.w += t.w;
        }
        float4 sc;
        sc.x = __expf(m4.x - mn.x); sc.y = __expf(m4.y - mn.y);
        sc.z = __expf(m4.z - mn.z); sc.w = __expf(m4.w - mn.w);
        z4.x = z4.x * sc.x + zc.x; z4.y = z4.y * sc.y + zc.y;
        z4.z = z4.z * sc.z + zc.z; z4.w = z4.w * sc.w + zc.w;
        float asc = sel4(sc, hd);
        #pragma unroll
        for (int u = 0; u < 8; ++u) acc[u] *= asc;
        alds[w][lane] = p4;   // p4=0, s=0 beyond cnt -> harmless row-0 reads
        slds[w][lane] = s;
        #pragma unroll 4
        for (int eb = 0; eb < cnt; eb += 2) {
            int e = eb + e2;
            float a = sel4(alds[w][e], hd);
            int ss = slds[w][e];
            int4 hv = *(const int4*)&hb[(size_t)ss * 256 + c8 * 8];
            uint32_t hx = (uint32_t)hv.x, hy = (uint32_t)hv.y;
            uint32_t hz = (uint32_t)hv.z, hw = (uint32_t)hv.w;
            acc[0] += a * bf2f_lo(hx); acc[1] += a * bf2f_hi(hx);
            acc[2] += a * bf2f_lo(hy); acc[3] += a * bf2f_hi(hy);
            acc[4] += a * bf2f_lo(hz); acc[5] += a * bf2f_hi(hz);
            acc[6] += a * bf2f_lo(hw); acc[7] += a * bf2f_hi(hw);
        }
        m4 = mn;
    }

    // combine the two edge subslots
    #pragma unroll
    for (int u = 0; u < 8; ++u) acc[u] += __shfl_xor(acc[u], 32, 64);

    if (e2 == 0) {
        float rz = 1.f / sel4(z4, hd);
        float4 b0 = *(const float4*)&bias[c8 * 8];
        float4 b1 = *(const float4*)&bias[c8 * 8 + 4];
        ushort4 o0, o1;
        o0.x = f2bf(fmaxf(acc[0] * rz + b0.x, 0.f));
        o0.y = f2bf(fmaxf(acc[1] * rz + b0.y, 0.f));
        o0.z = f2bf(fmaxf(acc[2] * rz + b0.z, 0.f));
        o0.w = f2bf(fmaxf(acc[3] * rz + b0.w, 0.f));
        o1.x = f2bf(fmaxf(acc[4] * rz + b1.x, 0.f));
        o1.y = f2bf(fmaxf(acc[5] * rz + b1.y, 0.f));
        o1.z = f2bf(fmaxf(acc[6] * rz + b1.z, 0.f));
        o1.w = f2bf(fmaxf(acc[7] * rz + b1.w, 0.f));
        *(ushort4*)&outb[(size_t)node * 256 + c8 * 8] = o0;
        *(ushort4*)&outb[(size_t)node * 256 + c8 * 8 + 4] = o1;
    }
}

// ---------------- GAT agg, layer 2 (H=1, 64 ch, bf16 in/out) ----------------
// lane = es*8 + c8: 8 lanes x ushort8 (16B) cover the 128B row; 8 edges/iter.

__global__ __launch_bounds__(256) void gat_agg_h1b_k(
    const unsigned short* __restrict__ hb, const float* __restrict__ al_s,
    const float* __restrict__ al_d, const int* __restrict__ offs,
    const int* __restrict__ csr_src, const float* __restrict__ bias,
    unsigned short* __restrict__ outb, int N)
{
    __shared__ float alds[4][64];
    __shared__ int   slds[4][64];
    int w = threadIdx.x >> 6, lane = threadIdx.x & 63;
    int node = blockIdx.x * 4 + w;
    if (node >= N) return;
    int es = lane >> 3, c8 = lane & 7;
    int beg = offs[node], end = offs[node + 1];
    float ald = al_d[node];
    float m_run = -1e30f, z_run = 0.f;
    float acc[8] = {};

    for (int base = beg; base < end; base += 64) {
        int cnt = min(64, end - base);
        int s = 0; float l = -1e30f;
        if (lane < cnt) {
            s = csr_src[base + lane];
            l = lrelu(al_s[s] + ald);
        }
        float mc = l;
        #pragma unroll
        for (int d = 32; d; d >>= 1) mc = fmaxf(mc, __shfl_xor(mc, d, 64));
        float mn = fmaxf(m_run, mc);
        float p = __expf(l - mn);
        float zc = p;
        #pragma unroll
        for (int d = 32; d; d >>= 1) zc += __shfl_xor(zc, d, 64);
        float sc = __expf(m_run - mn);
        z_run = z_run * sc + zc;
        #pragma unroll
        for (int u = 0; u < 8; ++u) acc[u] *= sc;
        alds[w][lane] = p;
        slds[w][lane] = s;
        #pragma unroll 2
        for (int eb = 0; eb < cnt; eb += 8) {
            int e = eb + es;
            float a = alds[w][e];
            int ss = slds[w][e];
            int4 hv = *(const int4*)&hb[(size_t)ss * 64 + c8 * 8];
            uint32_t hx = (uint32_t)hv.x, hy = (uint32_t)hv.y;
            uint32_t hz = (uint32_t)hv.z, hw = (uint32_t)hv.w;
            acc[0] += a * bf2f_lo(hx); acc[1] += a * bf2f_hi(hx);
            acc[2] += a * bf2f_lo(hy); acc[3] += a * bf2f_hi(hy);
            acc[4] += a * bf2f_lo(hz); acc[5] += a * bf2f_hi(hz);
            acc[6] += a * bf2f_lo(hw); acc[7] += a * bf2f_hi(hw);
        }
        m_run = mn;
    }

    // combine the 8 edge subslots
    #pragma unroll
    for (int u = 0; u < 8; ++u) {
        acc[u] += __shfl_xor(acc[u], 8, 64);
        acc[u] += __shfl_xor(acc[u], 16, 64);
        acc[u] += __shfl_xor(acc[u], 32, 64);
    }
    if (es == 0) {
        float rz = 1.f / z_run;
        float4 b0 = *(const float4*)&bias[c8 * 8];
        float4 b1 = *(const float4*)&bias[c8 * 8 + 4];
        ushort4 o0, o1;
        o0.x = f2bf(acc[0] * rz + b0.x);
        o0.y = f2bf(acc[1] * rz + b0.y);
        o0.z = f2bf(acc[2] * rz + b0.z);
        o0.w = f2bf(acc[3] * rz + b0.w);
        o1.x = f2bf(acc[4] * rz + b1.x);
        o1.y = f2bf(acc[5] * rz + b1.y);
        o1.z = f2bf(acc[6] * rz + b1.z);
        o1.w = f2bf(acc[7] * rz + b1.w);
        *(ushort4*)&outb[(size_t)node * 64 + c8 * 8] = o0;
        *(ushort4*)&outb[(size_t)node * 64 + c8 * 8 + 4] = o1;
    }
}

// ---------------- launch ----------------

extern "C" void kernel_launch(void* const* d_in, const int* in_sizes, int n_in,
                              void* d_out, int out_size, void* d_ws, size_t ws_size,
                              hipStream_t stream) {
    const float* x   = (const float*)d_in[0];
    const int*   ei  = (const int*)d_in[1];
    const float* W1  = (const float*)d_in[2];
    const float* as1 = (const float*)d_in[3];
    const float* ad1 = (const float*)d_in[4];
    const float* b1  = (const float*)d_in[5];
    const float* W2  = (const float*)d_in[6];
    const float* as2 = (const float*)d_in[7];
    const float* ad2 = (const float*)d_in[8];
    const float* b2  = (const float*)d_in[9];
    const float* Wf  = (const float*)d_in[10];
    const float* bf  = (const float*)d_in[11];
    float* out = (float*)d_out;

    int N = in_sizes[0] / 256;   // 50000
    int E = in_sizes[1] / 2;     // 800000
    int ET = E + N;
    int NB = (N + 1023) / 1024;  // 49 scan blocks

    char* w = (char*)d_ws;
    float* big   = (float*)w;                                 // N*256 f32 region (overlays)
    unsigned short* out1b = (unsigned short*)(w + (size_t)N * 256 * 4);  // N*256 bf16
    char*  p     = w + (size_t)N * 256 * 4 * 2;
    unsigned short* h1b = (unsigned short*)p;  p += (size_t)N * 256 * 2;
    float* al_s1 = (float*)p;            p += (size_t)N * 4 * 4;
    float* al_d1 = (float*)p;            p += (size_t)N * 4 * 4;
    float* al_s2 = (float*)p;            p += (size_t)N * 4;
    float* al_d2 = (float*)p;            p += (size_t)N * 4;
    int* counts  = (int*)p;              p += (size_t)N * 4;
    int* offs    = (int*)p;              p += (size_t)(N + 1) * 4 + 12;  // keep 16B alignment
    int* cursor  = (int*)p;              p += (size_t)N * 4;
    int* csr_src = (int*)p;              p += (size_t)ET * 4;
    int* bsum    = (int*)p;              p += 64 * 4;
    int* boff    = (int*)p;              p += 64 * 4;
    unsigned short* W1bT = (unsigned short*)p;  p += (size_t)256 * 256 * 2;
    unsigned short* W2bT = (unsigned short*)p;  p += (size_t)64 * 256 * 2;
    unsigned short* WfbT = (unsigned short*)p;  p += (size_t)256 * 64 * 2;
    // overlays in `big` (lifetimes disjoint):
    unsigned short* h2b   = (unsigned short*)big;                  // N*64 bf16 (layer 2)
    unsigned short* out2b = (unsigned short*)big + (size_t)N * 64; // N*64 bf16

    // CSR build
    hipMemsetAsync(counts, 0, (size_t)N * sizeof(int), stream);
    count_edges_k<<<(ET + 255) / 256, 256, 0, stream>>>(ei, counts, E, N);
    scan_bsum_k<<<NB, 1024, 0, stream>>>(counts, bsum, N);
    scan_boff_k<<<1, 64, 0, stream>>>(bsum, boff, NB);
    scan_final_k<<<NB, 1024, 0, stream>>>(counts, boff, offs, cursor, N);
    fill_csr_k<<<(ET + 255) / 256, 256, 0, stream>>>(ei, cursor, csr_src, E, N);

    // weight converts
    wt_k<<<256, 256, 0, stream>>>(W1, W1bT, 256, 256);
    wt_k<<<64, 256, 0, stream>>>(W2, W2bT, 256, 64);
    wt_k<<<256, 64, 0, stream>>>(Wf, WfbT, 64, 256);

    // layer 1: h1b = bf16(x @ W1), convert fused into A-staging, att fused into epilogue
    {
        dim3 g((N + 127) / 128, 2);
        gemm_mfma_k<256, 128, 4, true, true, false, true><<<g, 256, 0, stream>>>(
            nullptr, x, W1bT, nullptr, as1, ad1, al_s1, al_d1, h1b, nullptr, N, 256);
    }
    gat_agg_h4b_k<<<(N + 3) / 4, 256, 0, stream>>>(h1b, al_s1, al_d1, offs, csr_src, b1, out1b, N);

    // layer 2: h2b = bf16(out1b @ W2), 64x64 tiles
    gemm_mfma64_k<<<(N + 63) / 64, 256, 0, stream>>>(out1b, W2bT, h2b, N);
    att_b_k<<<N, 64, 0, stream>>>(h2b, as2, ad2, al_s2, al_d2, 1, 64);
    gat_agg_h1b_k<<<(N + 3) / 4, 256, 0, stream>>>(h2b, al_s2, al_d2, offs, csr_src, b2, out2b, N);

    // final: out = out2b @ Wf + bf (f32 out)
    {
        dim3 g((N + 127) / 128, 2);
        gemm_mfma_k<64, 128, 4, false, false, true, false><<<g, 256, 0, stream>>>(
            out2b, nullptr, WfbT, bf, nullptr, nullptr, nullptr, nullptr, nullptr, out, N, 256);
    }
}

// Round 12
// 273.490 us; speedup vs baseline: 1.0779x; 1.0779x over previous
//
#include <hip/hip_runtime.h>
#include <cstddef>
#include <cstdint>

// ---------------- bf16 helpers ----------------

__device__ __forceinline__ unsigned short f2bf(float f) {
    uint32_t u = __float_as_uint(f);
    u += 0x7FFFu + ((u >> 16) & 1u);
    return (unsigned short)(u >> 16);
}
__device__ __forceinline__ uint32_t f2bf2(float lo, float hi) {
    return (uint32_t)f2bf(lo) | ((uint32_t)f2bf(hi) << 16);
}
__device__ __forceinline__ float bf2f(unsigned short b) {
    return __uint_as_float(((uint32_t)b) << 16);
}

typedef __attribute__((ext_vector_type(8))) short bf16x8;
typedef __attribute__((ext_vector_type(4))) float f32x4;

// ---------------- CSR construction ----------------

__global__ void count_edges_k(const int* __restrict__ ei, int* __restrict__ counts,
                              int E, int N) {
    int e = blockIdx.x * blockDim.x + threadIdx.x;
    int tot = E + N;
    if (e >= tot) return;
    int d = (e < E) ? ei[E + e] : (e - E);
    atomicAdd(&counts[d], 1);
}

// multi-block scan, phase 1: per-1024-chunk sums
__global__ __launch_bounds__(1024) void scan_bsum_k(const int* __restrict__ counts,
                                                    int* __restrict__ bsum, int N) {
    __shared__ int wsum[16];
    int tid = threadIdx.x, lane = tid & 63, w = tid >> 6;
    int i = blockIdx.x * 1024 + tid;
    int x = (i < N) ? counts[i] : 0;
    #pragma unroll
    for (int d = 32; d; d >>= 1) x += __shfl_xor(x, d, 64);
    if (lane == 0) wsum[w] = x;
    __syncthreads();
    if (tid == 0) {
        int s = 0;
        #pragma unroll
        for (int k = 0; k < 16; ++k) s += wsum[k];
        bsum[blockIdx.x] = s;
    }
}

// phase 2: exclusive scan of block sums (nb <= 64)
__global__ void scan_boff_k(const int* __restrict__ bsum, int* __restrict__ boff, int nb) {
    int lane = threadIdx.x;
    int v = (lane < nb) ? bsum[lane] : 0;
    int x = v;
    #pragma unroll
    for (int d = 1; d < 64; d <<= 1) {
        int t = __shfl_up(x, d, 64);
        if (lane >= d) x += t;
    }
    if (lane < nb) boff[lane] = x - v;
}

// phase 3: per-chunk scan + global base -> offs/cursor
__global__ __launch_bounds__(1024) void scan_final_k(const int* __restrict__ counts,
                                                     const int* __restrict__ boff,
                                                     int* __restrict__ offs,
                                                     int* __restrict__ cursor, int N) {
    __shared__ int wsum[16];
    int tid = threadIdx.x, lane = tid & 63, w = tid >> 6;
    int i = blockIdx.x * 1024 + tid;
    int v = (i < N) ? counts[i] : 0;
    int x = v;
    #pragma unroll
    for (int d = 1; d < 64; d <<= 1) {
        int t = __shfl_up(x, d, 64);
        if (lane >= d) x += t;
    }
    if (lane == 63) wsum[w] = x;
    __syncthreads();
    if (tid == 0) {
        int run = 0;
        #pragma unroll
        for (int k = 0; k < 16; ++k) { run += wsum[k]; wsum[k] = run; }
    }
    __syncthreads();
    int excl = (x - v) + (w > 0 ? wsum[w - 1] : 0) + boff[blockIdx.x];
    if (i < N) { cursor[i] = excl; offs[i + 1] = excl + v; }
    if (i == 0) offs[0] = 0;
}

__global__ void fill_csr_k(const int* __restrict__ ei, int* __restrict__ cursor,
                           int* __restrict__ csr_src, int E, int N) {
    int e = blockIdx.x * blockDim.x + threadIdx.x;
    int tot = E + N;
    if (e >= tot) return;
    int s, d;
    if (e < E) { s = ei[e]; d = ei[E + e]; }
    else       { s = e - E; d = s; }
    int pos = atomicAdd(&cursor[d], 1);
    csr_src[pos] = s;
}

// ---------------- fused weight converts: W -> WT bf16 for all three weights ----------------
// blocks 0..255: W1 (256x256); 256..319: W2 (256x64); 320..575: Wf (64x256)

__global__ void wt_all_k(const float* __restrict__ W1, unsigned short* __restrict__ W1T,
                         const float* __restrict__ W2, unsigned short* __restrict__ W2T,
                         const float* __restrict__ Wf, unsigned short* __restrict__ WfT) {
    int b = blockIdx.x;
    int t = threadIdx.x;
    if (b < 256) {                 // W1: [256][256] -> W1T[n][k], n = b
        W1T[b * 256 + t] = f2bf(W1[t * 256 + b]);
    } else if (b < 320) {          // W2: [256][64] -> W2T[n][k], n = b-256, k = t
        int n = b - 256;
        W2T[n * 256 + t] = f2bf(W2[t * 64 + n]);
    } else {                       // Wf: [64][256] -> WfT[n][k], n = b-320, k = t&63 (4 n per block)
        int n = b - 320;
        if (t < 64) WfT[n * 64 + t] = f2bf(Wf[t * 256 + n]);
    }
}

// ---------------- generalized MFMA bf16 GEMM ----------------

template<int KD, int BN, int NI, bool AF32, bool OUTB, bool HASBIAS, bool FUSEATT>
__global__ __launch_bounds__(256) void gemm_mfma_k(
    const unsigned short* __restrict__ Ab,
    const float* __restrict__ Af,
    const unsigned short* __restrict__ BT,
    const float* __restrict__ bias,
    const float* __restrict__ att_s,
    const float* __restrict__ att_d,
    float* __restrict__ al_s,
    float* __restrict__ al_d,
    unsigned short* __restrict__ Cb,
    float* __restrict__ Cf,
    int M, int Nc)
{
    const int SA = 40;
    __shared__ unsigned short As[128 * SA];
    __shared__ unsigned short Bs[BN * SA];
    int tid = threadIdx.x;
    int lane = tid & 63, wid = tid >> 6;
    int wm = wid >> 1, wn = wid & 1;
    int bm = blockIdx.x * 128, bn = blockIdx.y * BN;

    f32x4 acc[4][NI];
    #pragma unroll
    for (int mi = 0; mi < 4; ++mi)
        #pragma unroll
        for (int ni = 0; ni < NI; ++ni) {
            acc[mi][ni][0] = 0.f; acc[mi][ni][1] = 0.f;
            acc[mi][ni][2] = 0.f; acc[mi][ni][3] = 0.f;
        }

    int srow = tid >> 2;
    int skc  = tid & 3;

    for (int k0 = 0; k0 < KD; k0 += 32) {
        #pragma unroll
        for (int q = 0; q < 2; ++q) {
            int row = q * 64 + srow;
            int gr = bm + row;
            int4 av = make_int4(0, 0, 0, 0);
            if (AF32) {
                float4 a0 = make_float4(0.f, 0.f, 0.f, 0.f), a1 = a0;
                if (gr < M) {
                    a0 = *(const float4*)&Af[(size_t)gr * KD + k0 + skc * 8];
                    a1 = *(const float4*)&Af[(size_t)gr * KD + k0 + skc * 8 + 4];
                }
                av.x = (int)f2bf2(a0.x, a0.y);
                av.y = (int)f2bf2(a0.z, a0.w);
                av.z = (int)f2bf2(a1.x, a1.y);
                av.w = (int)f2bf2(a1.z, a1.w);
            } else {
                if (gr < M) av = *(const int4*)&Ab[(size_t)gr * KD + k0 + skc * 8];
            }
            *(int4*)&As[row * SA + skc * 8] = av;
        }
        #pragma unroll
        for (int q = 0; q < BN / 64; ++q) {
            int row = q * 64 + srow;
            int4 bv = *(const int4*)&BT[(size_t)(bn + row) * KD + k0 + skc * 8];
            *(int4*)&Bs[row * SA + skc * 8] = bv;
        }
        __syncthreads();

        bf16x8 af[4], bfv[NI];
        #pragma unroll
        for (int mi = 0; mi < 4; ++mi)
            af[mi] = *(const bf16x8*)&As[(wm * 64 + mi * 16 + (lane & 15)) * SA + (lane >> 4) * 8];
        #pragma unroll
        for (int ni = 0; ni < NI; ++ni)
            bfv[ni] = *(const bf16x8*)&Bs[(wn * (NI * 16) + ni * 16 + (lane & 15)) * SA + (lane >> 4) * 8];
        #pragma unroll
        for (int mi = 0; mi < 4; ++mi)
            #pragma unroll
            for (int ni = 0; ni < NI; ++ni)
                acc[mi][ni] = __builtin_amdgcn_mfma_f32_16x16x32_bf16(af[mi], bfv[ni], acc[mi][ni], 0, 0, 0);
        __syncthreads();
    }

    #pragma unroll
    for (int mi = 0; mi < 4; ++mi) {
        #pragma unroll
        for (int j = 0; j < 4; ++j) {
            int row = bm + wm * 64 + mi * 16 + (lane >> 4) * 4 + j;
            if (row >= M) continue;
            #pragma unroll
            for (int ni = 0; ni < NI; ++ni) {
                int col = bn + wn * (NI * 16) + ni * 16 + (lane & 15);
                if (OUTB) {
                    Cb[(size_t)row * Nc + col] = f2bf(acc[mi][ni][j]);
                } else {
                    float v = acc[mi][ni][j] + (HASBIAS ? bias[col] : 0.f);
                    Cf[(size_t)row * Nc + col] = v;
                }
            }
        }
    }

    if (FUSEATT) {
        int head = (bn >> 6) + wn;
        float asv[NI], adv[NI];
        #pragma unroll
        for (int ni = 0; ni < NI; ++ni) {
            int c = head * 64 + ni * 16 + (lane & 15);
            asv[ni] = att_s[c];
            adv[ni] = att_d[c];
        }
        #pragma unroll
        for (int mi = 0; mi < 4; ++mi) {
            #pragma unroll
            for (int j = 0; j < 4; ++j) {
                float sp = 0.f, dp = 0.f;
                #pragma unroll
                for (int ni = 0; ni < NI; ++ni) {
                    sp += acc[mi][ni][j] * asv[ni];
                    dp += acc[mi][ni][j] * adv[ni];
                }
                #pragma unroll
                for (int d = 1; d < 16; d <<= 1) {
                    sp += __shfl_xor(sp, d, 64);
                    dp += __shfl_xor(dp, d, 64);
                }
                int row = bm + wm * 64 + mi * 16 + (lane >> 4) * 4 + j;
                if ((lane & 15) == 0 && row < M) {
                    al_s[(size_t)row * 4 + head] = sp;
                    al_d[(size_t)row * 4 + head] = dp;
                }
            }
        }
    }
}

// ---------------- 64x64 MFMA GEMM (GEMM2) ----------------

__global__ __launch_bounds__(256) void gemm_mfma64_k(
    const unsigned short* __restrict__ Ab,
    const unsigned short* __restrict__ BT,
    unsigned short* __restrict__ Cb,
    int M)
{
    const int SA = 40;
    __shared__ unsigned short As[64 * SA];
    __shared__ unsigned short Bs[64 * SA];
    int tid = threadIdx.x;
    int lane = tid & 63, wid = tid >> 6;
    int wm = wid >> 1, wn = wid & 1;
    int bm = blockIdx.x * 64;

    f32x4 acc[2][2];
    #pragma unroll
    for (int mi = 0; mi < 2; ++mi)
        #pragma unroll
        for (int ni = 0; ni < 2; ++ni) {
            acc[mi][ni][0] = 0.f; acc[mi][ni][1] = 0.f;
            acc[mi][ni][2] = 0.f; acc[mi][ni][3] = 0.f;
        }

    int srow = tid >> 2;
    int skc  = tid & 3;

    for (int k0 = 0; k0 < 256; k0 += 32) {
        {
            int gr = bm + srow;
            int4 av = make_int4(0, 0, 0, 0);
            if (gr < M) av = *(const int4*)&Ab[(size_t)gr * 256 + k0 + skc * 8];
            *(int4*)&As[srow * SA + skc * 8] = av;
            int4 bv = *(const int4*)&BT[(size_t)srow * 256 + k0 + skc * 8];
            *(int4*)&Bs[srow * SA + skc * 8] = bv;
        }
        __syncthreads();

        bf16x8 af[2], bfv[2];
        #pragma unroll
        for (int mi = 0; mi < 2; ++mi)
            af[mi] = *(const bf16x8*)&As[(wm * 32 + mi * 16 + (lane & 15)) * SA + (lane >> 4) * 8];
        #pragma unroll
        for (int ni = 0; ni < 2; ++ni)
            bfv[ni] = *(const bf16x8*)&Bs[(wn * 32 + ni * 16 + (lane & 15)) * SA + (lane >> 4) * 8];
        #pragma unroll
        for (int mi = 0; mi < 2; ++mi)
            #pragma unroll
            for (int ni = 0; ni < 2; ++ni)
                acc[mi][ni] = __builtin_amdgcn_mfma_f32_16x16x32_bf16(af[mi], bfv[ni], acc[mi][ni], 0, 0, 0);
        __syncthreads();
    }

    #pragma unroll
    for (int mi = 0; mi < 2; ++mi) {
        #pragma unroll
        for (int j = 0; j < 4; ++j) {
            int row = bm + wm * 32 + mi * 16 + (lane >> 4) * 4 + j;
            if (row >= M) continue;
            #pragma unroll
            for (int ni = 0; ni < 2; ++ni) {
                int col = wn * 32 + ni * 16 + (lane & 15);
                Cb[(size_t)row * 64 + col] = f2bf(acc[mi][ni][j]);
            }
        }
    }
}

// ---------------- per-node attention logits (bf16 input) ----------------

__global__ void att_b_k(const unsigned short* __restrict__ hb, const float* __restrict__ as_,
                        const float* __restrict__ ad_, float* __restrict__ al_s,
                        float* __restrict__ al_d, int H, int C) {
    int n = blockIdx.x;
    int t = threadIdx.x;
    int hd = t / C;
    int c = t % C;
    float hv = bf2f(hb[(size_t)n * H * C + t]);
    float ps = hv * as_[t];
    float pd = hv * ad_[t];
    #pragma unroll
    for (int d = 32; d > 0; d >>= 1) {
        ps += __shfl_down(ps, d, 64);
        pd += __shfl_down(pd, d, 64);
    }
    if (c == 0) {
        al_s[(size_t)n * H + hd] = ps;
        al_d[(size_t)n * H + hd] = pd;
    }
}

// ---------------- float4 helpers ----------------

__device__ __forceinline__ float4 shflx4(float4 v, int d) {
    float4 r;
    r.x = __shfl_xor(v.x, d, 64);
    r.y = __shfl_xor(v.y, d, 64);
    r.z = __shfl_xor(v.z, d, 64);
    r.w = __shfl_xor(v.w, d, 64);
    return r;
}
__device__ __forceinline__ float4 max4(float4 a, float4 b) {
    return make_float4(fmaxf(a.x, b.x), fmaxf(a.y, b.y), fmaxf(a.z, b.z), fmaxf(a.w, b.w));
}
__device__ __forceinline__ float sel4(float4 v, int i) {
    float ab = (i & 1) ? v.y : v.x;
    float cd = (i & 1) ? v.w : v.z;
    return (i & 2) ? cd : ab;
}
__device__ __forceinline__ float lrelu(float t) { return (t > 0.f) ? t : 0.2f * t; }

// ---------------- GAT agg, layer 1 (H=4, 256 ch, bf16 in/out) ----------------
// R10 geometry (40 VGPR, unroll-4 gather) + grid-stride node loop so blocks
// are long-lived (CP dispatch rate was capping occupancy at ~54%).

__global__ __launch_bounds__(256) void gat_agg_h4b_k(
    const unsigned short* __restrict__ hb, const float* __restrict__ al_s,
    const float* __restrict__ al_d, const int* __restrict__ offs,
    const int* __restrict__ csr_src, const float* __restrict__ bias,
    unsigned short* __restrict__ outb, int N)
{
    __shared__ float4 alds[4][64];
    __shared__ int    slds[4][64];
    int w = threadIdx.x >> 6, lane = threadIdx.x & 63;
    int hd = lane >> 4;
    int stride = gridDim.x * 4;
    float4 b4 = *(const float4*)&bias[lane * 4];

    for (int node = blockIdx.x * 4 + w; node < N; node += stride) {
        int beg = offs[node], end = offs[node + 1];
        float4 ald4 = *(const float4*)&al_d[(size_t)node * 4];
        float4 m4 = make_float4(-1e30f, -1e30f, -1e30f, -1e30f);
        float4 z4 = make_float4(0.f, 0.f, 0.f, 0.f);
        float4 acc = make_float4(0.f, 0.f, 0.f, 0.f);

        for (int base = beg; base < end; base += 64) {
            int cnt = min(64, end - base);
            int s = 0;
            float4 l4 = make_float4(-1e30f, -1e30f, -1e30f, -1e30f);
            if (lane < cnt) {
                s = csr_src[base + lane];
                float4 as4 = *(const float4*)&al_s[(size_t)s * 4];
                l4.x = lrelu(as4.x + ald4.x);
                l4.y = lrelu(as4.y + ald4.y);
                l4.z = lrelu(as4.z + ald4.z);
                l4.w = lrelu(as4.w + ald4.w);
            }
            float4 mc = l4;
            #pragma unroll
            for (int d = 32; d; d >>= 1) mc = max4(mc, shflx4(mc, d));
            float4 mn = max4(m4, mc);
            float4 p4;
            p4.x = __expf(l4.x - mn.x);   // 0 for inactive lanes
            p4.y = __expf(l4.y - mn.y);
            p4.z = __expf(l4.z - mn.z);
            p4.w = __expf(l4.w - mn.w);
            float4 zc = p4;
            #pragma unroll
            for (int d = 32; d; d >>= 1) {
                float4 t = shflx4(zc, d);
                zc.x += t.x; zc.y += t.y; zc.z += t.z; zc.w += t.w;
            }
            float4 sc;
            sc.x = __expf(m4.x - mn.x); sc.y = __expf(m4.y - mn.y);
            sc.z = __expf(m4.z - mn.z); sc.w = __expf(m4.w - mn.w);
            z4.x = z4.x * sc.x + zc.x; z4.y = z4.y * sc.y + zc.y;
            z4.z = z4.z * sc.z + zc.z; z4.w = z4.w * sc.w + zc.w;
            float asc = sel4(sc, hd);
            acc.x *= asc; acc.y *= asc; acc.z *= asc; acc.w *= asc;
            alds[w][lane] = p4;
            slds[w][lane] = s;
            #pragma unroll 4
            for (int e = 0; e < cnt; ++e) {
                float a = sel4(alds[w][e], hd);
                int ss = slds[w][e];
                ushort4 hv = *(const ushort4*)&hb[(size_t)ss * 256 + lane * 4];
                acc.x += a * bf2f(hv.x); acc.y += a * bf2f(hv.y);
                acc.z += a * bf2f(hv.z); acc.w += a * bf2f(hv.w);
            }
            m4 = mn;
        }

        float rz = 1.f / sel4(z4, hd);
        ushort4 o;
        o.x = f2bf(fmaxf(acc.x * rz + b4.x, 0.f));
        o.y = f2bf(fmaxf(acc.y * rz + b4.y, 0.f));
        o.z = f2bf(fmaxf(acc.z * rz + b4.z, 0.f));
        o.w = f2bf(fmaxf(acc.w * rz + b4.w, 0.f));
        *(ushort4*)&outb[(size_t)node * 256 + lane * 4] = o;
    }
}

// ---------------- GAT agg, layer 2 (H=1, 64 ch, bf16 in/out) ----------------
// R10 geometry (4 edge-subslots, ushort4) + grid-stride node loop.

__global__ __launch_bounds__(256) void gat_agg_h1b_k(
    const unsigned short* __restrict__ hb, const float* __restrict__ al_s,
    const float* __restrict__ al_d, const int* __restrict__ offs,
    const int* __restrict__ csr_src, const float* __restrict__ bias,
    unsigned short* __restrict__ outb, int N)
{
    __shared__ float alds[4][64];
    __shared__ int   slds[4][64];
    int w = threadIdx.x >> 6, lane = threadIdx.x & 63;
    int es = lane >> 4, c4 = lane & 15;
    int stride = gridDim.x * 4;
    float4 b4 = *(const float4*)&bias[c4 * 4];

    for (int node = blockIdx.x * 4 + w; node < N; node += stride) {
        int beg = offs[node], end = offs[node + 1];
        float ald = al_d[node];
        float m_run = -1e30f, z_run = 0.f;
        float4 acc = make_float4(0.f, 0.f, 0.f, 0.f);

        for (int base = beg; base < end; base += 64) {
            int cnt = min(64, end - base);
            int s = 0; float l = -1e30f;
            if (lane < cnt) {
                s = csr_src[base + lane];
                l = lrelu(al_s[s] + ald);
            }
            float mc = l;
            #pragma unroll
            for (int d = 32; d; d >>= 1) mc = fmaxf(mc, __shfl_xor(mc, d, 64));
            float mn = fmaxf(m_run, mc);
            float p = __expf(l - mn);
            float zc = p;
            #pragma unroll
            for (int d = 32; d; d >>= 1) zc += __shfl_xor(zc, d, 64);
            float sc = __expf(m_run - mn);
            z_run = z_run * sc + zc;
            acc.x *= sc; acc.y *= sc; acc.z *= sc; acc.w *= sc;
            alds[w][lane] = p;
            slds[w][lane] = s;
            for (int eb = 0; eb < cnt; eb += 4) {
                int e = eb + es;
                float a = alds[w][e];
                int ss = slds[w][e];
                ushort4 hv = *(const ushort4*)&hb[(size_t)ss * 64 + c4 * 4];
                acc.x += a * bf2f(hv.x); acc.y += a * bf2f(hv.y);
                acc.z += a * bf2f(hv.z); acc.w += a * bf2f(hv.w);
            }
            m_run = mn;
        }

        float4 t = shflx4(acc, 16);
        acc.x += t.x; acc.y += t.y; acc.z += t.z; acc.w += t.w;
        t = shflx4(acc, 32);
        acc.x += t.x; acc.y += t.y; acc.z += t.z; acc.w += t.w;
        if (es == 0) {
            float rz = 1.f / z_run;
            ushort4 o;
            o.x = f2bf(acc.x * rz + b4.x);
            o.y = f2bf(acc.y * rz + b4.y);
            o.z = f2bf(acc.z * rz + b4.z);
            o.w = f2bf(acc.w * rz + b4.w);
            *(ushort4*)&outb[(size_t)node * 64 + c4 * 4] = o;
        }
    }
}

// ---------------- launch ----------------

extern "C" void kernel_launch(void* const* d_in, const int* in_sizes, int n_in,
                              void* d_out, int out_size, void* d_ws, size_t ws_size,
                              hipStream_t stream) {
    const float* x   = (const float*)d_in[0];
    const int*   ei  = (const int*)d_in[1];
    const float* W1  = (const float*)d_in[2];
    const float* as1 = (const float*)d_in[3];
    const float* ad1 = (const float*)d_in[4];
    const float* b1  = (const float*)d_in[5];
    const float* W2  = (const float*)d_in[6];
    const float* as2 = (const float*)d_in[7];
    const float* ad2 = (const float*)d_in[8];
    const float* b2  = (const float*)d_in[9];
    const float* Wf  = (const float*)d_in[10];
    const float* bf  = (const float*)d_in[11];
    float* out = (float*)d_out;

    int N = in_sizes[0] / 256;   // 50000
    int E = in_sizes[1] / 2;     // 800000
    int ET = E + N;
    int NB = (N + 1023) / 1024;  // 49 scan blocks

    char* w = (char*)d_ws;
    float* big   = (float*)w;                                 // N*256 f32 region (overlays)
    unsigned short* out1b = (unsigned short*)(w + (size_t)N * 256 * 4);  // N*256 bf16
    char*  p     = w + (size_t)N * 256 * 4 * 2;
    unsigned short* h1b = (unsigned short*)p;  p += (size_t)N * 256 * 2;
    float* al_s1 = (float*)p;            p += (size_t)N * 4 * 4;
    float* al_d1 = (float*)p;            p += (size_t)N * 4 * 4;
    float* al_s2 = (float*)p;            p += (size_t)N * 4;
    float* al_d2 = (float*)p;            p += (size_t)N * 4;
    int* counts  = (int*)p;              p += (size_t)N * 4;
    int* offs    = (int*)p;              p += (size_t)(N + 1) * 4 + 12;  // keep 16B alignment
    int* cursor  = (int*)p;              p += (size_t)N * 4;
    int* csr_src = (int*)p;              p += (size_t)ET * 4;
    int* bsum    = (int*)p;              p += 64 * 4;
    int* boff    = (int*)p;              p += 64 * 4;
    unsigned short* W1bT = (unsigned short*)p;  p += (size_t)256 * 256 * 2;
    unsigned short* W2bT = (unsigned short*)p;  p += (size_t)64 * 256 * 2;
    unsigned short* WfbT = (unsigned short*)p;  p += (size_t)256 * 64 * 2;
    // overlays in `big` (lifetimes disjoint):
    unsigned short* h2b   = (unsigned short*)big;                  // N*64 bf16 (layer 2)
    unsigned short* out2b = (unsigned short*)big + (size_t)N * 64; // N*64 bf16

    // CSR build
    hipMemsetAsync(counts, 0, (size_t)N * sizeof(int), stream);
    count_edges_k<<<(ET + 255) / 256, 256, 0, stream>>>(ei, counts, E, N);
    scan_bsum_k<<<NB, 1024, 0, stream>>>(counts, bsum, N);
    scan_boff_k<<<1, 64, 0, stream>>>(bsum, boff, NB);
    scan_final_k<<<NB, 1024, 0, stream>>>(counts, boff, offs, cursor, N);
    fill_csr_k<<<(ET + 255) / 256, 256, 0, stream>>>(ei, cursor, csr_src, E, N);

    // weight converts (single fused launch)
    wt_all_k<<<576, 256, 0, stream>>>(W1, W1bT, W2, W2bT, Wf, WfbT);

    // layer 1: h1b = bf16(x @ W1), convert fused into A-staging, att fused into epilogue
    {
        dim3 g((N + 127) / 128, 2);
        gemm_mfma_k<256, 128, 4, true, true, false, true><<<g, 256, 0, stream>>>(
            nullptr, x, W1bT, nullptr, as1, ad1, al_s1, al_d1, h1b, nullptr, N, 256);
    }
    {
        int nblk = min(2048, (N + 3) / 4);
        gat_agg_h4b_k<<<nblk, 256, 0, stream>>>(h1b, al_s1, al_d1, offs, csr_src, b1, out1b, N);
    }

    // layer 2: h2b = bf16(out1b @ W2), 64x64 tiles
    gemm_mfma64_k<<<(N + 63) / 64, 256, 0, stream>>>(out1b, W2bT, h2b, N);
    att_b_k<<<N, 64, 0, stream>>>(h2b, as2, ad2, al_s2, al_d2, 1, 64);
    {
        int nblk = min(2048, (N + 3) / 4);
        gat_agg_h1b_k<<<nblk, 256, 0, stream>>>(h2b, al_s2, al_d2, offs, csr_src, b2, out2b, N);
    }

    // final: out = out2b @ Wf + bf (f32 out)
    {
        dim3 g((N + 127) / 128, 2);
        gemm_mfma_k<64, 128, 4, false, false, true, false><<<g, 256, 0, stream>>>(
            out2b, nullptr, WfbT, bf, nullptr, nullptr, nullptr, nullptr, nullptr, out, N, 256);
    }
}